// Round 8
// baseline (231.829 us; speedup 1.0000x reference)
//
#include <hip/hip_runtime.h>
#include <math.h>

#define BB 8
#define CC 64
#define NA 4096   // H*W
#define KA 32     // C_a
#define LOG2E 1.4426950408889634f

typedef short bfrag __attribute__((ext_vector_type(8)));   // 8 bf16 = 4 VGPRs
typedef int   i4    __attribute__((ext_vector_type(4)));
typedef float f4    __attribute__((ext_vector_type(4)));
typedef float f16v  __attribute__((ext_vector_type(16)));

__device__ __forceinline__ f16v mf(bfrag a, bfrag b, f16v c) {
    return __builtin_amdgcn_mfma_f32_32x32x16_bf16(a, b, c, 0, 0, 0);
}

// round-to-nearest-even fp32 -> bf16 bits
__device__ __forceinline__ unsigned short bfrne(float f) {
    unsigned u = __builtin_bit_cast(unsigned, f);
    return (unsigned short)((u + 0x7FFFu + ((u >> 16) & 1u)) >> 16);
}
__device__ __forceinline__ unsigned pk2(float a, float b) {
    return (unsigned)bfrne(a) | ((unsigned)bfrne(b) << 16);
}
__device__ __forceinline__ float bf2f(unsigned short h) {
    unsigned u = ((unsigned)h) << 16;
    return __builtin_bit_cast(float, u);
}

// ---------------- Kernel 1: g = W*x + b -> bf16 hi/lo split [b][n][k], norms,
//                  batch max-norm (atomicMax), zero lsum ----------------
__global__ __launch_bounds__(256) void k_g(const float* __restrict__ x,
                                           const float* __restrict__ W,
                                           const float* __restrict__ bias,
                                           short* __restrict__ ghi,
                                           short* __restrict__ glo,
                                           float* __restrict__ norms,
                                           int* __restrict__ gmaxi,
                                           float* __restrict__ lsum) {
    __shared__ float Wl[KA * CC];
    __shared__ float bl[KA];
    __shared__ float red[4];
    int tid = threadIdx.x;
    for (int i = tid; i < KA * CC; i += 256) Wl[i] = W[i];
    if (tid < KA) bl[tid] = bias[tid];
    __syncthreads();

    int b = blockIdx.y;
    int n = blockIdx.x * 256 + tid;

    float acc[KA];
#pragma unroll
    for (int k = 0; k < KA; k++) acc[k] = 0.f;

    const float* xp = x + (size_t)b * CC * NA + n;
#pragma unroll 4
    for (int c = 0; c < CC; c++) {
        float xv = xp[(size_t)c * NA];
#pragma unroll
        for (int k = 0; k < KA; k++) acc[k] = fmaf(Wl[k * CC + c], xv, acc[k]);
    }

    float ss = 0.f;
    unsigned ph[KA / 2], pl[KA / 2];
#pragma unroll
    for (int k = 0; k < KA; k += 2) {
        float v0 = acc[k] + bl[k];
        float v1 = acc[k + 1] + bl[k + 1];
        ss = fmaf(v0, v0, fmaf(v1, v1, ss));
        unsigned short h0 = bfrne(v0), h1 = bfrne(v1);
        float l0 = v0 - bf2f(h0), l1 = v1 - bf2f(h1);
        ph[k / 2] = (unsigned)h0 | ((unsigned)h1 << 16);
        pl[k / 2] = (unsigned)bfrne(l0) | ((unsigned)bfrne(l1) << 16);
    }
    float nrm = sqrtf(ss);
    norms[b * NA + n] = nrm;
    lsum[b * NA + n] = 0.f;   // zero accumulator for k_den (each call: replay-safe)

    size_t row = ((size_t)b * NA + n) * KA;  // in shorts
#pragma unroll
    for (int q = 0; q < 4; q++) {
        i4 vh = { (int)ph[4 * q], (int)ph[4 * q + 1], (int)ph[4 * q + 2], (int)ph[4 * q + 3] };
        i4 vl = { (int)pl[4 * q], (int)pl[4 * q + 1], (int)pl[4 * q + 2], (int)pl[4 * q + 3] };
        *(i4*)(ghi + row + q * 8) = vh;
        *(i4*)(glo + row + q * 8) = vl;
    }

    // block max -> atomicMax (positive floats: int compare == float compare;
    // stale value from previous replay equals current max -> idempotent)
    float m = nrm;
#pragma unroll
    for (int off = 1; off < 64; off <<= 1) m = fmaxf(m, __shfl_xor(m, off));
    if ((tid & 63) == 0) red[tid >> 6] = m;
    __syncthreads();
    if (tid == 0) {
        float bm = fmaxf(fmaxf(red[0], red[1]), fmaxf(red[2], red[3]));
        atomicMax(&gmaxi[b], __float_as_int(bm));
    }
}

// ---------------- Kernel 1c: x -> bf16 transpose-copy xb2[b][m>>3][c][m&7] ----------------
__global__ __launch_bounds__(256) void k_xb(const float* __restrict__ x,
                                            short* __restrict__ xb2) {
    __shared__ float t[64][65];
    const int tid = threadIdx.x;
    const int b = blockIdx.y;
    const int m0 = blockIdx.x * 64;

    const int c0 = tid >> 4, m4 = (tid & 15) * 4;
#pragma unroll
    for (int p = 0; p < 4; p++) {
        int c = p * 16 + c0;
        f4 v = *(const f4*)(x + ((size_t)b * CC + c) * NA + m0 + m4);
        t[c][m4 + 0] = v[0];
        t[c][m4 + 1] = v[1];
        t[c][m4 + 2] = v[2];
        t[c][m4 + 3] = v[3];
    }
    __syncthreads();

    short* xo = xb2 + (size_t)b * CC * NA;
#pragma unroll
    for (int q = 0; q < 2; q++) {
        int idx = q * 256 + tid;
        int mgl = idx >> 6, c = idx & 63;
        i4 pkd;
#pragma unroll
        for (int j = 0; j < 4; j++)
            pkd[j] = (int)pk2(t[c][mgl * 8 + 2 * j], t[c][mgl * 8 + 2 * j + 1]);
        *(i4*)(xo + (size_t)(((m0 >> 3) + mgl) * 64 + c) * 8) = pkd;
    }
}

// ---------------- Kernel 2a: denominators (pass 1), m-split x4, atomicAdd ----------------
__global__ __launch_bounds__(256, 4) void k_den(const short* __restrict__ ghi,
                                                const short* __restrict__ glo,
                                                const float* __restrict__ norms,
                                                const int* __restrict__ gmaxi,
                                                float* __restrict__ lsum) {
    __shared__ float rowsum[4][32];
    const int tid = threadIdx.x;
    const int w = tid >> 6;
    const int l31 = tid & 31;
    const int hi = (tid >> 5) & 1;
    const int id = blockIdx.x;
    const int b = id & 7;
    const int rr = id >> 3;
    const int nb = rr & 127;
    const int mc = rr >> 7;
    const int n0 = nb * 32;

    const float gmax = __int_as_float(gmaxi[b]);
    const float C2 = -norms[b * NA + n0 + l31] * gmax * LOG2E;
    const short* gh = ghi + (size_t)b * NA * KA;
    const short* gl = glo + (size_t)b * NA * KA;

    bfrag Bh[2], Bl[2];
#pragma unroll
    for (int kt = 0; kt < 2; kt++) {
        size_t o = (size_t)(n0 + l31) * KA + kt * 16 + hi * 8;
        Bh[kt] = *(const bfrag*)(gh + o);
        Bl[kt] = *(const bfrag*)(gl + o);
    }

    float ls = 0.f;
#pragma unroll 2
    for (int i = 0; i < 8; i++) {
        const int m0 = (mc * 8 + i) * 128 + w * 32;
        bfrag Ah[2], Al[2];
#pragma unroll
        for (int kt = 0; kt < 2; kt++) {
            size_t o = (size_t)(m0 + l31) * KA + kt * 16 + hi * 8;
            Ah[kt] = *(const bfrag*)(gh + o);
            Al[kt] = *(const bfrag*)(gl + o);
        }
        f16v sA = {}, sB = {};
        sA = mf(Ah[0], Bh[0], sA); sA = mf(Ah[1], Bh[1], sA);
        sB = mf(Ah[0], Bl[0], sB); sB = mf(Ah[1], Bl[1], sB);
        sB = mf(Al[0], Bh[0], sB); sB = mf(Al[1], Bh[1], sB);
#pragma unroll
        for (int r = 0; r < 16; r++) ls += exp2f(fmaf(sA[r] + sB[r], LOG2E, C2));
    }
    ls += __shfl_xor(ls, 32);
    if (hi == 0) rowsum[w][l31] = ls;
    __syncthreads();
    if (tid < 32)
        atomicAdd(&lsum[b * NA + n0 + tid],
                  rowsum[0][tid] + rowsum[1][tid] + rowsum[2][tid] + rowsum[3][tid]);
}

// ---------------- Kernel 3: pass 2 — alpha + PV ----------------
// MT=512 m per iter (8 iters), astage double-buffered 2x[32][512] f32 = 128 KB
// (1 block/CU), ONE barrier per iter; store bursts = 2 KB contiguous per row.
// grid 1024: b = id&7 (XCD-pinned batch), n0 = (id>>3)*32
__global__ __launch_bounds__(256, 1) void k_attn2(const float* __restrict__ x,
                                                  const short* __restrict__ ghi,
                                                  const short* __restrict__ glo,
                                                  const short* __restrict__ xb2,
                                                  const float* __restrict__ norms,
                                                  const int* __restrict__ gmaxi,
                                                  const float* __restrict__ lsum,
                                                  float* __restrict__ out,
                                                  float* __restrict__ alpha) {
    __shared__ __align__(16) char smem[2 * 32 * 512 * 4];   // 128 KB: astage dbuf
    float* ast = (float*)smem;

    const int tid = threadIdx.x;
    const int w = tid >> 6;
    const int l = tid & 63;
    const int l31 = tid & 31;
    const int hi = (tid >> 5) & 1;
    const int id = blockIdx.x;
    const int b = id & 7;
    const int n0 = (id >> 3) * 32;

    const float M = norms[b * NA + n0 + l31] * __int_as_float(gmaxi[b]);
    const float C2L = fmaf(-M, LOG2E, -__log2f(lsum[b * NA + n0 + l31]));

    const short* gh = ghi + (size_t)b * NA * KA;
    const short* gl = glo + (size_t)b * NA * KA;
    const short* xp = xb2 + (size_t)b * CC * NA;
    float* ap = alpha + (size_t)b * NA * NA;

    // persistent B-fragments (block rows n)
    bfrag Bh[2], Bl[2];
#pragma unroll
    for (int kt = 0; kt < 2; kt++) {
        size_t o = (size_t)(n0 + l31) * KA + kt * 16 + hi * 8;
        Bh[kt] = *(const bfrag*)(gh + o);
        Bl[kt] = *(const bfrag*)(gl + o);
    }

    f16v pv0 = {}, pv1 = {};

    for (int it = 0; it < 8; ++it) {
        float* astb = ast + (it & 1) * 16384;

        // ---- fill phase: 4 sub-tiles of 128 m ----
#pragma unroll
        for (int sub = 0; sub < 4; ++sub) {
            const int m0 = it * 512 + sub * 128 + w * 32;
            bfrag Ah[2], Al[2];
#pragma unroll
            for (int kt = 0; kt < 2; kt++) {
                size_t o = (size_t)(m0 + l31) * KA + kt * 16 + hi * 8;
                Ah[kt] = *(const bfrag*)(gh + o);
                Al[kt] = *(const bfrag*)(gl + o);
            }
            f16v sA = {}, sB = {};
            sA = mf(Ah[0], Bh[0], sA); sA = mf(Ah[1], Bh[1], sA);
            sB = mf(Ah[0], Bl[0], sB); sB = mf(Ah[1], Bl[1], sB);
            sB = mf(Al[0], Bh[0], sB); sB = mf(Al[1], Bh[1], sB);

            float a[16];
#pragma unroll
            for (int r = 0; r < 16; r++) a[r] = exp2f(fmaf(sA[r] + sB[r], LOG2E, C2L));

            // stage (swizzled 16B chunks)
#pragma unroll
            for (int q = 0; q < 4; q++) {
                f4 v = { a[4 * q], a[4 * q + 1], a[4 * q + 2], a[4 * q + 3] };
                int phys = (w * 8 + 2 * q + hi) ^ (l31 & 7);
                *(f4*)&astb[l31 * 512 + sub * 128 + phys * 4] = v;
            }

            // pack P -> bf16 A-fragments (verified permlane recipe)
            unsigned p0 = pk2(a[0], a[1]),   p1 = pk2(a[2], a[3]);
            unsigned p2 = pk2(a[4], a[5]),   p3 = pk2(a[6], a[7]);
            unsigned p4 = pk2(a[8], a[9]),   p5 = pk2(a[10], a[11]);
            unsigned p6 = pk2(a[12], a[13]), p7 = pk2(a[14], a[15]);
            asm("v_permlane32_swap_b32 %0, %1" : "+v"(p0), "+v"(p2));
            asm("v_permlane32_swap_b32 %0, %1" : "+v"(p1), "+v"(p3));
            asm("v_permlane32_swap_b32 %0, %1" : "+v"(p4), "+v"(p6));
            asm("v_permlane32_swap_b32 %0, %1" : "+v"(p5), "+v"(p7));
            i4 f0 = { (int)p0, (int)p1, (int)p2, (int)p3 };
            i4 f1 = { (int)p4, (int)p5, (int)p6, (int)p7 };
            bfrag pa0 = __builtin_bit_cast(bfrag, f0);
            bfrag pa1 = __builtin_bit_cast(bfrag, f1);

            // X B-fragments from xb2[m>>3][c][m&7]: 512B contiguous per 32 lanes
            const int mg = m0 >> 3;
            bfrag X00 = *(const bfrag*)(xp + (size_t)((mg + hi) * 64 + l31) * 8);
            bfrag X01 = *(const bfrag*)(xp + (size_t)((mg + 2 + hi) * 64 + l31) * 8);
            bfrag X10 = *(const bfrag*)(xp + (size_t)((mg + hi) * 64 + 32 + l31) * 8);
            bfrag X11 = *(const bfrag*)(xp + (size_t)((mg + 2 + hi) * 64 + 32 + l31) * 8);

            pv0 = mf(pa0, X00, pv0); pv0 = mf(pa1, X01, pv0);
            pv1 = mf(pa0, X10, pv1); pv1 = mf(pa1, X11, pv1);
        }

        __syncthreads();   // astb complete; prev iter's stores drained here

        // ---- store phase: 2 KB contiguous per row, non-temporal ----
        // wave w owns rows 8w..8w+7; per row 128 f4 chunks (2 passes of 64 lanes)
#pragma unroll
        for (int e = 0; e < 8; e++) {
            int row = w * 8 + e;
#pragma unroll
            for (int p = 0; p < 2; p++) {
                int c4 = p * 64 + l;
                int phys = (c4 & 31) ^ e;
                f4 v = *(const f4*)&astb[row * 512 + (c4 >> 5) * 128 + phys * 4];
                __builtin_nontemporal_store(v, (f4*)(ap + (size_t)(n0 + row) * NA + it * 512 + c4 * 4));
            }
        }
        // no second barrier: next iter fills the other buffer while stores drain
    }
    __syncthreads();

    // ---------------- cross-wave PV reduction (alias smem) ----------------
    float (*pvr0)[CC + 1] = (float(*)[CC + 1])smem;
    float (*pvr1)[CC + 1] = (float(*)[CC + 1])(smem + 32 * (CC + 1) * 4);
    if (w >= 2) {
        float (*buf)[CC + 1] = (w == 2) ? pvr0 : pvr1;
#pragma unroll
        for (int r = 0; r < 16; r++) {
            int nl = (r & 3) + 8 * (r >> 2) + 4 * hi;
            buf[nl][l31]      = pv0[r];
            buf[nl][32 + l31] = pv1[r];
        }
    }
    __syncthreads();
    if (w < 2) {
        float (*buf)[CC + 1] = (w == 0) ? pvr0 : pvr1;
#pragma unroll
        for (int r = 0; r < 16; r++) {
            int nl = (r & 3) + 8 * (r >> 2) + 4 * hi;
            buf[nl][l31]      += pv0[r];
            buf[nl][32 + l31] += pv1[r];
        }
    }
    __syncthreads();

    // ---------------- epilogue: residual + relu ----------------
    const float* xr = x + (size_t)b * CC * NA + n0;
    float* op = out + (size_t)b * CC * NA + n0;
#pragma unroll
    for (int e = 0; e < 8; e++) {
        int idx = e * 256 + tid;
        int c = idx >> 5, n = idx & 31;
        float v = pvr0[n][c] + pvr1[n][c] + xr[(size_t)c * NA + n];
        op[(size_t)c * NA + n] = fmaxf(v, 0.f);
    }
}

extern "C" void kernel_launch(void* const* d_in, const int* in_sizes, int n_in,
                              void* d_out, int out_size, void* d_ws, size_t ws_size,
                              hipStream_t stream) {
    const float* x = (const float*)d_in[0];
    const float* W = (const float*)d_in[1];
    const float* bias = (const float*)d_in[2];

    float* out = (float*)d_out;
    float* alpha = out + (size_t)BB * CC * NA;  // outputs concatenated: out then alpha

    short* ghi = (short*)d_ws;                       // [B][NA][KA] bf16 hi
    short* glo = ghi + (size_t)BB * NA * KA;         // bf16 lo
    short* xb2 = glo + (size_t)BB * NA * KA;         // [B][NA/8][CC][8] bf16
    float* norms = (float*)(xb2 + (size_t)BB * CC * NA);
    int*   gmaxi = (int*)(norms + (size_t)BB * NA);  // [B]
    float* lsum  = (float*)(gmaxi + 8);              // [B][NA]

    k_g<<<dim3(NA / 256, BB), 256, 0, stream>>>(x, W, bias, ghi, glo, norms, gmaxi, lsum);
    k_xb<<<dim3(NA / 64, BB), 256, 0, stream>>>(x, xb2);
    k_den<<<4096, 256, 0, stream>>>(ghi, glo, norms, gmaxi, lsum);
    k_attn2<<<1024, 256, 0, stream>>>(x, ghi, glo, xb2, norms, gmaxi, lsum, out, alpha);
}

// Round 9
// 180.861 us; speedup vs baseline: 1.2818x; 1.2818x over previous
//
#include <hip/hip_runtime.h>
#include <math.h>

#define BB 8
#define CC 64
#define NA 4096   // H*W
#define KA 32     // C_a
#define LOG2E 1.4426950408889634f

typedef short bfrag __attribute__((ext_vector_type(8)));   // 8 bf16 = 4 VGPRs
typedef int   i4    __attribute__((ext_vector_type(4)));
typedef float f4    __attribute__((ext_vector_type(4)));
typedef float f16v  __attribute__((ext_vector_type(16)));

__device__ __forceinline__ f16v mf(bfrag a, bfrag b, f16v c) {
    return __builtin_amdgcn_mfma_f32_32x32x16_bf16(a, b, c, 0, 0, 0);
}

// round-to-nearest-even fp32 -> bf16 bits
__device__ __forceinline__ unsigned short bfrne(float f) {
    unsigned u = __builtin_bit_cast(unsigned, f);
    return (unsigned short)((u + 0x7FFFu + ((u >> 16) & 1u)) >> 16);
}
__device__ __forceinline__ unsigned pk2(float a, float b) {
    return (unsigned)bfrne(a) | ((unsigned)bfrne(b) << 16);
}
__device__ __forceinline__ float bf2f(unsigned short h) {
    unsigned u = ((unsigned)h) << 16;
    return __builtin_bit_cast(float, u);
}

// ---------------- Kernel 1: g = W*x + b -> bf16 hi/lo split [b][n][k], norms,
//                  batch max-norm (atomicMax), zero lsum ----------------
__global__ __launch_bounds__(256) void k_g(const float* __restrict__ x,
                                           const float* __restrict__ W,
                                           const float* __restrict__ bias,
                                           short* __restrict__ ghi,
                                           short* __restrict__ glo,
                                           float* __restrict__ norms,
                                           int* __restrict__ gmaxi,
                                           float* __restrict__ lsum) {
    __shared__ float Wl[KA * CC];
    __shared__ float bl[KA];
    __shared__ float red[4];
    int tid = threadIdx.x;
    for (int i = tid; i < KA * CC; i += 256) Wl[i] = W[i];
    if (tid < KA) bl[tid] = bias[tid];
    __syncthreads();

    int b = blockIdx.y;
    int n = blockIdx.x * 256 + tid;

    float acc[KA];
#pragma unroll
    for (int k = 0; k < KA; k++) acc[k] = 0.f;

    const float* xp = x + (size_t)b * CC * NA + n;
#pragma unroll 4
    for (int c = 0; c < CC; c++) {
        float xv = xp[(size_t)c * NA];
#pragma unroll
        for (int k = 0; k < KA; k++) acc[k] = fmaf(Wl[k * CC + c], xv, acc[k]);
    }

    float ss = 0.f;
    unsigned ph[KA / 2], pl[KA / 2];
#pragma unroll
    for (int k = 0; k < KA; k += 2) {
        float v0 = acc[k] + bl[k];
        float v1 = acc[k + 1] + bl[k + 1];
        ss = fmaf(v0, v0, fmaf(v1, v1, ss));
        unsigned short h0 = bfrne(v0), h1 = bfrne(v1);
        float l0 = v0 - bf2f(h0), l1 = v1 - bf2f(h1);
        ph[k / 2] = (unsigned)h0 | ((unsigned)h1 << 16);
        pl[k / 2] = (unsigned)bfrne(l0) | ((unsigned)bfrne(l1) << 16);
    }
    float nrm = sqrtf(ss);
    norms[b * NA + n] = nrm;
    lsum[b * NA + n] = 0.f;   // zero accumulator for k_den (each call: replay-safe)

    size_t row = ((size_t)b * NA + n) * KA;  // in shorts
#pragma unroll
    for (int q = 0; q < 4; q++) {
        i4 vh = { (int)ph[4 * q], (int)ph[4 * q + 1], (int)ph[4 * q + 2], (int)ph[4 * q + 3] };
        i4 vl = { (int)pl[4 * q], (int)pl[4 * q + 1], (int)pl[4 * q + 2], (int)pl[4 * q + 3] };
        *(i4*)(ghi + row + q * 8) = vh;
        *(i4*)(glo + row + q * 8) = vl;
    }

    // block max -> atomicMax (positive floats: int compare == float compare;
    // stale value from previous replay equals current max -> idempotent)
    float m = nrm;
#pragma unroll
    for (int off = 1; off < 64; off <<= 1) m = fmaxf(m, __shfl_xor(m, off));
    if ((tid & 63) == 0) red[tid >> 6] = m;
    __syncthreads();
    if (tid == 0) {
        float bm = fmaxf(fmaxf(red[0], red[1]), fmaxf(red[2], red[3]));
        atomicMax(&gmaxi[b], __float_as_int(bm));
    }
}

// ---------------- Kernel 1c: x -> bf16 transpose-copy xb2[b][m>>3][c][m&7] ----------------
__global__ __launch_bounds__(256) void k_xb(const float* __restrict__ x,
                                            short* __restrict__ xb2) {
    __shared__ float t[64][65];
    const int tid = threadIdx.x;
    const int b = blockIdx.y;
    const int m0 = blockIdx.x * 64;

    const int c0 = tid >> 4, m4 = (tid & 15) * 4;
#pragma unroll
    for (int p = 0; p < 4; p++) {
        int c = p * 16 + c0;
        f4 v = *(const f4*)(x + ((size_t)b * CC + c) * NA + m0 + m4);
        t[c][m4 + 0] = v[0];
        t[c][m4 + 1] = v[1];
        t[c][m4 + 2] = v[2];
        t[c][m4 + 3] = v[3];
    }
    __syncthreads();

    short* xo = xb2 + (size_t)b * CC * NA;
#pragma unroll
    for (int q = 0; q < 2; q++) {
        int idx = q * 256 + tid;
        int mgl = idx >> 6, c = idx & 63;
        i4 pkd;
#pragma unroll
        for (int j = 0; j < 4; j++)
            pkd[j] = (int)pk2(t[c][mgl * 8 + 2 * j], t[c][mgl * 8 + 2 * j + 1]);
        *(i4*)(xo + (size_t)(((m0 >> 3) + mgl) * 64 + c) * 8) = pkd;
    }
}

// ---------------- Kernel 2a: denominators (pass 1), m-split x4, atomicAdd ----------------
__global__ __launch_bounds__(256, 4) void k_den(const short* __restrict__ ghi,
                                                const short* __restrict__ glo,
                                                const float* __restrict__ norms,
                                                const int* __restrict__ gmaxi,
                                                float* __restrict__ lsum) {
    __shared__ float rowsum[4][32];
    const int tid = threadIdx.x;
    const int w = tid >> 6;
    const int l31 = tid & 31;
    const int hi = (tid >> 5) & 1;
    const int id = blockIdx.x;
    const int b = id & 7;
    const int rr = id >> 3;
    const int nb = rr & 127;
    const int mc = rr >> 7;
    const int n0 = nb * 32;

    const float gmax = __int_as_float(gmaxi[b]);
    const float C2 = -norms[b * NA + n0 + l31] * gmax * LOG2E;
    const short* gh = ghi + (size_t)b * NA * KA;
    const short* gl = glo + (size_t)b * NA * KA;

    bfrag Bh[2], Bl[2];
#pragma unroll
    for (int kt = 0; kt < 2; kt++) {
        size_t o = (size_t)(n0 + l31) * KA + kt * 16 + hi * 8;
        Bh[kt] = *(const bfrag*)(gh + o);
        Bl[kt] = *(const bfrag*)(gl + o);
    }

    float ls = 0.f;
#pragma unroll 2
    for (int i = 0; i < 8; i++) {
        const int m0 = (mc * 8 + i) * 128 + w * 32;
        bfrag Ah[2], Al[2];
#pragma unroll
        for (int kt = 0; kt < 2; kt++) {
            size_t o = (size_t)(m0 + l31) * KA + kt * 16 + hi * 8;
            Ah[kt] = *(const bfrag*)(gh + o);
            Al[kt] = *(const bfrag*)(gl + o);
        }
        f16v sA = {}, sB = {};
        sA = mf(Ah[0], Bh[0], sA); sA = mf(Ah[1], Bh[1], sA);
        sB = mf(Ah[0], Bl[0], sB); sB = mf(Ah[1], Bl[1], sB);
        sB = mf(Al[0], Bh[0], sB); sB = mf(Al[1], Bh[1], sB);
#pragma unroll
        for (int r = 0; r < 16; r++) ls += exp2f(fmaf(sA[r] + sB[r], LOG2E, C2));
    }
    ls += __shfl_xor(ls, 32);
    if (hi == 0) rowsum[w][l31] = ls;
    __syncthreads();
    if (tid < 32)
        atomicAdd(&lsum[b * NA + n0 + tid],
                  rowsum[0][tid] + rowsum[1][tid] + rowsum[2][tid] + rowsum[3][tid]);
}

// fragment load macros (static indices; dst must be a bfrag[4] lvalue base)
#define LOADA(dst, m0v) do { \
    size_t _o = (size_t)((m0v) + l31) * KA + hi * 8; \
    dst[0] = *(const bfrag*)(gh + _o); \
    dst[1] = *(const bfrag*)(gh + _o + 16); \
    dst[2] = *(const bfrag*)(gl + _o); \
    dst[3] = *(const bfrag*)(gl + _o + 16); } while (0)

#define LOADX(dst, m0v) do { \
    const int _mg = (m0v) >> 3; \
    dst[0] = *(const bfrag*)(xp + (size_t)((_mg + hi) * 64 + l31) * 8); \
    dst[1] = *(const bfrag*)(xp + (size_t)((_mg + 2 + hi) * 64 + l31) * 8); \
    dst[2] = *(const bfrag*)(xp + (size_t)((_mg + hi) * 64 + 32 + l31) * 8); \
    dst[3] = *(const bfrag*)(xp + (size_t)((_mg + 2 + hi) * 64 + 32 + l31) * 8); } while (0)

// ---------------- Kernel 3: pass 2 — alpha + PV (r7 + store-decoupled pipeline) ----------------
// MT=256 m per iter (16 iters), astage double-buffered, lgkm-ONLY barrier per iter
// (no vmcnt(0) drain: nt stores stay in flight across iters). A/X fragments are
// prefetched one subtile ahead so every load is issued BEFORE the iter's stores
// in program order -> in-order vmcnt never makes MFMA wait on store drain.
// grid 1024: b = id&7 (XCD-pinned batch), n0 = (id>>3)*32
__global__ __launch_bounds__(256, 2) void k_attn2(const float* __restrict__ x,
                                                  const short* __restrict__ ghi,
                                                  const short* __restrict__ glo,
                                                  const short* __restrict__ xb2,
                                                  const float* __restrict__ norms,
                                                  const int* __restrict__ gmaxi,
                                                  const float* __restrict__ lsum,
                                                  float* __restrict__ out,
                                                  float* __restrict__ alpha) {
    __shared__ __align__(16) char smem[2 * 32 * 256 * 4];   // 64 KB: astage dbuf
    float* ast = (float*)smem;

    const int tid = threadIdx.x;
    const int w = tid >> 6;
    const int l = tid & 63;
    const int l31 = tid & 31;
    const int hi = (tid >> 5) & 1;
    const int id = blockIdx.x;
    const int b = id & 7;
    const int n0 = (id >> 3) * 32;

    const float M = norms[b * NA + n0 + l31] * __int_as_float(gmaxi[b]);
    const float C2L = fmaf(-M, LOG2E, -__log2f(lsum[b * NA + n0 + l31]));

    const short* gh = ghi + (size_t)b * NA * KA;
    const short* gl = glo + (size_t)b * NA * KA;
    const short* xp = xb2 + (size_t)b * CC * NA;
    float* ap = alpha + (size_t)b * NA * NA;

    // persistent B-fragments (block rows n)
    bfrag Bh[2], Bl[2];
#pragma unroll
    for (int kt = 0; kt < 2; kt++) {
        size_t o = (size_t)(n0 + l31) * KA + kt * 16 + hi * 8;
        Bh[kt] = *(const bfrag*)(gh + o);
        Bl[kt] = *(const bfrag*)(gl + o);
    }

    f16v pv0 = {}, pv1 = {};

    // two fragment slots (per subtile phase), prefetch distance = 1 subtile
    bfrag Af0[4], Af1[4], Xf0[4], Xf1[4];
    LOADA(Af0, w * 32);
    LOADX(Xf0, w * 32);

    for (int it = 0; it < 16; ++it) {
        float* astb = ast + (it & 1) * 8192;
        const int mb = it * 256 + w * 32;

        // ======== sub 0: consume slot0; prefetch slot1 = (it, sub1) ========
        LOADA(Af1, mb + 128);
        LOADX(Xf1, mb + 128);
        {
            f16v sA = {}, sB = {};
            sA = mf(Af0[0], Bh[0], sA); sA = mf(Af0[1], Bh[1], sA);
            sB = mf(Af0[0], Bl[0], sB); sB = mf(Af0[1], Bl[1], sB);
            sB = mf(Af0[2], Bh[0], sB); sB = mf(Af0[3], Bh[1], sB);

            float a[16];
#pragma unroll
            for (int r = 0; r < 16; r++) a[r] = exp2f(fmaf(sA[r] + sB[r], LOG2E, C2L));

#pragma unroll
            for (int q = 0; q < 4; q++) {
                f4 v = { a[4 * q], a[4 * q + 1], a[4 * q + 2], a[4 * q + 3] };
                int phys = (w * 8 + 2 * q + hi) ^ (l31 & 7);
                *(f4*)&astb[l31 * 256 + phys * 4] = v;
            }

            unsigned p0 = pk2(a[0], a[1]),   p1 = pk2(a[2], a[3]);
            unsigned p2 = pk2(a[4], a[5]),   p3 = pk2(a[6], a[7]);
            unsigned p4 = pk2(a[8], a[9]),   p5 = pk2(a[10], a[11]);
            unsigned p6 = pk2(a[12], a[13]), p7 = pk2(a[14], a[15]);
            asm("v_permlane32_swap_b32 %0, %1" : "+v"(p0), "+v"(p2));
            asm("v_permlane32_swap_b32 %0, %1" : "+v"(p1), "+v"(p3));
            asm("v_permlane32_swap_b32 %0, %1" : "+v"(p4), "+v"(p6));
            asm("v_permlane32_swap_b32 %0, %1" : "+v"(p5), "+v"(p7));
            i4 f0 = { (int)p0, (int)p1, (int)p2, (int)p3 };
            i4 f1 = { (int)p4, (int)p5, (int)p6, (int)p7 };
            bfrag pa0 = __builtin_bit_cast(bfrag, f0);
            bfrag pa1 = __builtin_bit_cast(bfrag, f1);

            pv0 = mf(pa0, Xf0[0], pv0); pv0 = mf(pa1, Xf0[1], pv0);
            pv1 = mf(pa0, Xf0[2], pv1); pv1 = mf(pa1, Xf0[3], pv1);
        }

        // ======== sub 1: consume slot1; prefetch slot0 = (it+1, sub0) ========
        if (it < 15) {
            LOADA(Af0, mb + 256);
            LOADX(Xf0, mb + 256);
        }
        {
            f16v sA = {}, sB = {};
            sA = mf(Af1[0], Bh[0], sA); sA = mf(Af1[1], Bh[1], sA);
            sB = mf(Af1[0], Bl[0], sB); sB = mf(Af1[1], Bl[1], sB);
            sB = mf(Af1[2], Bh[0], sB); sB = mf(Af1[3], Bh[1], sB);

            float a[16];
#pragma unroll
            for (int r = 0; r < 16; r++) a[r] = exp2f(fmaf(sA[r] + sB[r], LOG2E, C2L));

#pragma unroll
            for (int q = 0; q < 4; q++) {
                f4 v = { a[4 * q], a[4 * q + 1], a[4 * q + 2], a[4 * q + 3] };
                int phys = (w * 8 + 2 * q + hi) ^ (l31 & 7);
                *(f4*)&astb[l31 * 256 + 128 + phys * 4] = v;
            }

            unsigned p0 = pk2(a[0], a[1]),   p1 = pk2(a[2], a[3]);
            unsigned p2 = pk2(a[4], a[5]),   p3 = pk2(a[6], a[7]);
            unsigned p4 = pk2(a[8], a[9]),   p5 = pk2(a[10], a[11]);
            unsigned p6 = pk2(a[12], a[13]), p7 = pk2(a[14], a[15]);
            asm("v_permlane32_swap_b32 %0, %1" : "+v"(p0), "+v"(p2));
            asm("v_permlane32_swap_b32 %0, %1" : "+v"(p1), "+v"(p3));
            asm("v_permlane32_swap_b32 %0, %1" : "+v"(p4), "+v"(p6));
            asm("v_permlane32_swap_b32 %0, %1" : "+v"(p5), "+v"(p7));
            i4 f0 = { (int)p0, (int)p1, (int)p2, (int)p3 };
            i4 f1 = { (int)p4, (int)p5, (int)p6, (int)p7 };
            bfrag pa0 = __builtin_bit_cast(bfrag, f0);
            bfrag pa1 = __builtin_bit_cast(bfrag, f1);

            pv0 = mf(pa0, Xf1[0], pv0); pv0 = mf(pa1, Xf1[1], pv0);
            pv1 = mf(pa0, Xf1[2], pv1); pv1 = mf(pa1, Xf1[3], pv1);
        }

        // LDS-visibility barrier WITHOUT vmcnt drain (stores stay in flight)
        asm volatile("s_waitcnt lgkmcnt(0)\n\ts_barrier" ::: "memory");

        // ---- store phase: each inst = one full row x 1KB contiguous, non-temporal ----
#pragma unroll
        for (int e = 0; e < 8; e++) {
            int row = w * 8 + e;          // wave owns 8 rows; row&7 == e
            int c4 = l;                   // 64 f4 chunks per row
            int phys = (c4 & 31) ^ e;
            f4 v = *(const f4*)&astb[row * 256 + (c4 >> 5) * 128 + phys * 4];
            __builtin_nontemporal_store(v, (f4*)(ap + (size_t)(n0 + row) * NA + it * 256 + c4 * 4));
        }
        // no second barrier: next iter fills the other buffer while stores drain
    }
    __syncthreads();

    // ---------------- cross-wave PV reduction (alias smem) ----------------
    float (*pvr0)[CC + 1] = (float(*)[CC + 1])smem;
    float (*pvr1)[CC + 1] = (float(*)[CC + 1])(smem + 32 * (CC + 1) * 4);
    if (w >= 2) {
        float (*buf)[CC + 1] = (w == 2) ? pvr0 : pvr1;
#pragma unroll
        for (int r = 0; r < 16; r++) {
            int nl = (r & 3) + 8 * (r >> 2) + 4 * hi;
            buf[nl][l31]      = pv0[r];
            buf[nl][32 + l31] = pv1[r];
        }
    }
    __syncthreads();
    if (w < 2) {
        float (*buf)[CC + 1] = (w == 0) ? pvr0 : pvr1;
#pragma unroll
        for (int r = 0; r < 16; r++) {
            int nl = (r & 3) + 8 * (r >> 2) + 4 * hi;
            buf[nl][l31]      += pv0[r];
            buf[nl][32 + l31] += pv1[r];
        }
    }
    __syncthreads();

    // ---------------- epilogue: residual + relu ----------------
    const float* xr = x + (size_t)b * CC * NA + n0;
    float* op = out + (size_t)b * CC * NA + n0;
#pragma unroll
    for (int e = 0; e < 8; e++) {
        int idx = e * 256 + tid;
        int c = idx >> 5, n = idx & 31;
        float v = pvr0[n][c] + pvr1[n][c] + xr[(size_t)c * NA + n];
        op[(size_t)c * NA + n] = fmaxf(v, 0.f);
    }
}

extern "C" void kernel_launch(void* const* d_in, const int* in_sizes, int n_in,
                              void* d_out, int out_size, void* d_ws, size_t ws_size,
                              hipStream_t stream) {
    const float* x = (const float*)d_in[0];
    const float* W = (const float*)d_in[1];
    const float* bias = (const float*)d_in[2];

    float* out = (float*)d_out;
    float* alpha = out + (size_t)BB * CC * NA;  // outputs concatenated: out then alpha

    short* ghi = (short*)d_ws;                       // [B][NA][KA] bf16 hi
    short* glo = ghi + (size_t)BB * NA * KA;         // bf16 lo
    short* xb2 = glo + (size_t)BB * NA * KA;         // [B][NA/8][CC][8] bf16
    float* norms = (float*)(xb2 + (size_t)BB * CC * NA);
    int*   gmaxi = (int*)(norms + (size_t)BB * NA);  // [B]
    float* lsum  = (float*)(gmaxi + 8);              // [B][NA]

    k_g<<<dim3(NA / 256, BB), 256, 0, stream>>>(x, W, bias, ghi, glo, norms, gmaxi, lsum);
    k_xb<<<dim3(NA / 64, BB), 256, 0, stream>>>(x, xb2);
    k_den<<<4096, 256, 0, stream>>>(ghi, glo, norms, gmaxi, lsum);
    k_attn2<<<1024, 256, 0, stream>>>(x, ghi, glo, xb2, norms, gmaxi, lsum, out, alpha);
}